// Round 3
// baseline (272.420 us; speedup 1.0000x reference)
//
#include <hip/hip_runtime.h>

// NSLayer: per 8x8 matrix x: A = I - x x^T (symmetric),
// out = ((1+w7) I + w0 A + w1 A^2 + ... + w6 A^7) x.
//
// Decomposition: 2 lanes per matrix, lane h owns COLUMNS 4h..4h+3 of x/out.
// Rows are stored half-permuted per lane: p<4 -> global row 4h+p,
// p>=4 -> global row 4(1-h)+(p-4).  Partner's frame is mine composed with
// sigma(p)=p^4, so any symmetric-matrix entry transfers between lanes as
//   mine[p][q] = shfl_xor(partner[norm(p^4, q^4)], 1).
//
// R6 (matrix Horner): all Horner intermediates are polynomials in A
// -> symmetric and commuting with A. So build the matrix polynomial
//   R = w6 A^6 + ... + w0 I   via 5 symmetric products (upper triangle only),
//   M = R A + (1+w7) I        (6th product), then ONE matvec out = M x.
// Each symmetric product's 36 upper entries are split across the lane pair:
// 20 computed locally (10 UL + 6 crossing + 4 fixed points), 16 received
// via one shfl_xor each. Measured R8: 47.5us, VGPR 116, VALUBusy 49%,
// Occupancy 15.5% -> latency-bound at 2 waves/SIMD, NOT issue-bound.
//
// R9 change: __launch_bounds__(256, 2) -> (256, 4). VGPR 116 <= 128 so
// 4 waves/SIMD fits without spilling; the old bound was the only thing
// capping occupancy at 25%. Issue floor ~12us, memory floor ~16us; at
// 4 waves/SIMD expect ~28-32us (VALUBusy ~80%).
//
// Code-shape lesson (R2-R5): plain [8][8] arrays, upper-triangle writes only
// (dead elements SROA away), no packing, no waves_per_eu attribute.

#define SE(p, q) S[(p) < (q) ? (p) : (q)][(p) < (q) ? (q) : (p)]
#define AE(p, q) A[(p) < (q) ? (p) : (q)][(p) < (q) ? (q) : (p)]
#define UT(M, p, q) M[(p) < (q) ? (p) : (q)][(p) < (q) ? (q) : (p)]
// Lane-split membership for symmetric-product entries (upper triangle):
// computed set T = {q<4 (UL)} u {p+4<=q (chosen crossing + fixed points)}.
#define IN_T(p, q) ((q) < 4 || (p) + 4 <= (q))

// One matrix-Horner step: Pn = Po * A + wk * I  (all symmetric, upper only).
// Compute 20 entries locally, receive 16 from the partner lane.
#define MAT_STEP(Pn, Po, wk)                                              \
    {                                                                     \
        _Pragma("unroll")                                                 \
        for (int p = 0; p < 8; ++p) {                                     \
            _Pragma("unroll")                                             \
            for (int q = p; q < 8; ++q) {                                 \
                if (IN_T(p, q)) {                                         \
                    float s = (p == q) ? (wk) : 0.0f;                     \
                    _Pragma("unroll")                                     \
                    for (int r = 0; r < 8; ++r)                           \
                        s += UT(Po, p, r) * AE(r, q);                     \
                    Pn[p][q] = s;                                         \
                }                                                         \
            }                                                             \
        }                                                                 \
        _Pragma("unroll")                                                 \
        for (int p = 0; p < 8; ++p) {                                     \
            _Pragma("unroll")                                             \
            for (int q = p; q < 8; ++q) {                                 \
                if (!IN_T(p, q)) {                                        \
                    const int pa = (p) ^ 4, pb = (q) ^ 4;                 \
                    const int lo = pa < pb ? pa : pb;                     \
                    const int hi = pa < pb ? pb : pa;                     \
                    Pn[p][q] = __shfl_xor(Pn[lo][hi], 1);                 \
                }                                                         \
            }                                                             \
        }                                                                 \
    }

__global__ __launch_bounds__(256, 4)
void ns_poly_kernel(const float* __restrict__ in,
                    const float* __restrict__ wp,
                    float* __restrict__ out)
{
    const int tid = threadIdx.x;
    const int m   = blockIdx.x * 128 + (tid >> 1);   // matrix index
    const int h   = tid & 1;                          // column-half owner

    const float w0 = wp[0], w1 = wp[1], w2 = wp[2], w3 = wp[3];
    const float w4 = wp[4], w5 = wp[5], w6 = wp[6], w7 = wp[7];

    // ---- direct column-fragment loads (transpose by addressing) ----
    const float* bp      = in + (size_t)m * 64 + h * 4;
    const float* baseOwn = bp + h * 32;
    const float* basePar = bp + (1 - h) * 32;

    float xc[4][8];                                   // xc[jj][p]: col 4h+jj, permuted row p
#pragma unroll
    for (int p = 0; p < 4; ++p) {
        const float4 v = *reinterpret_cast<const float4*>(baseOwn + p * 8);
        xc[0][p] = v.x; xc[1][p] = v.y; xc[2][p] = v.z; xc[3][p] = v.w;
    }
#pragma unroll
    for (int p = 0; p < 4; ++p) {
        const float4 v = *reinterpret_cast<const float4*>(basePar + p * 8);
        xc[0][4 + p] = v.x; xc[1][4 + p] = v.y; xc[2][4 + p] = v.z; xc[3][4 + p] = v.w;
    }

    // ---- partial Gram S[p][q] = sum over my 4 columns (upper triangle) ----
    float S[8][8];
#pragma unroll
    for (int p = 0; p < 8; ++p)
#pragma unroll
        for (int q = p; q < 8; ++q) {
            float s = xc[0][p] * xc[0][q];
            s += xc[1][p] * xc[1][q];
            s += xc[2][p] * xc[2][q];
            s += xc[3][p] * xc[3][q];
            S[p][q] = s;
        }

    // ---- A = I - S - partner(S) (one shfl_xor per entry) ----
    float A[8][8];
#pragma unroll
    for (int p = 0; p < 8; ++p)
#pragma unroll
        for (int q = p; q < 8; ++q) {
            const float other = __shfl_xor(SE((p) ^ 4, (q) ^ 4), 1);
            A[p][q] = (p == q ? 1.0f : 0.0f) - S[p][q] - other;
        }

    // ---- matrix Horner on the upper triangle ----
    // P = w6 A + w5 I (elementwise init, full upper triangle)
    float P[8][8], Q[8][8];
#pragma unroll
    for (int p = 0; p < 8; ++p)
#pragma unroll
        for (int q = p; q < 8; ++q)
            P[p][q] = (p == q) ? fmaf(w6, A[p][q], w5) : w6 * A[p][q];

    MAT_STEP(Q, P, w4);           // w6 A^2 + w5 A + w4 I
    MAT_STEP(P, Q, w3);
    MAT_STEP(Q, P, w2);
    MAT_STEP(P, Q, w1);
    MAT_STEP(Q, P, w0);           // R = w6 A^6 + ... + w0 I
    MAT_STEP(P, Q, 1.0f + w7);    // M = R A + (1+w7) I

    // ---- single matvec: out columns = M * x columns (shuffle-free) ----
    float t[4][8];
#pragma unroll
    for (int jj = 0; jj < 4; ++jj)
#pragma unroll
        for (int p = 0; p < 8; ++p) {
            float s = UT(P, p, 0) * xc[jj][0];
#pragma unroll
            for (int q = 1; q < 8; ++q)
                s += UT(P, p, q) * xc[jj][q];
            t[jj][p] = s;
        }

    // ---- direct column-fragment stores (transpose by addressing) ----
    float* obp     = out + (size_t)m * 64 + h * 4;
    float* oandOwn = obp + h * 32;
    float* oandPar = obp + (1 - h) * 32;
#pragma unroll
    for (int p = 0; p < 4; ++p)
        *reinterpret_cast<float4*>(oandOwn + p * 8) =
            make_float4(t[0][p], t[1][p], t[2][p], t[3][p]);
#pragma unroll
    for (int p = 0; p < 4; ++p)
        *reinterpret_cast<float4*>(oandPar + p * 8) =
            make_float4(t[0][4 + p], t[1][4 + p], t[2][4 + p], t[3][4 + p]);
}

extern "C" void kernel_launch(void* const* d_in, const int* in_sizes, int n_in,
                              void* d_out, int out_size, void* d_ws, size_t ws_size,
                              hipStream_t stream)
{
    const float* in = (const float*)d_in[0];
    const float* w  = (const float*)d_in[1];
    float* outp     = (float*)d_out;

    const int nmat   = in_sizes[0] / 64;   // 262144 matrices
    const int blocks = nmat / 128;         // 128 matrices per 256-thread block
    ns_poly_kernel<<<blocks, 256, 0, stream>>>(in, w, outp);
}

// Round 4
// 123.450 us; speedup vs baseline: 2.2067x; 2.2067x over previous
//
#include <hip/hip_runtime.h>

// NSLayer: per 8x8 matrix x: A = I - x x^T (symmetric),
// out = ((1+w7) I + w0 A + w1 A^2 + ... + w6 A^7) x.
//
// Decomposition: 2 lanes per matrix, lane h owns COLUMNS 4h..4h+3 of x/out.
// Rows are stored half-permuted per lane: p<4 -> global row 4h+p,
// p>=4 -> global row 4(1-h)+(p-4).  Partner's frame is mine composed with
// sigma(p)=p^4, so any symmetric-matrix entry transfers between lanes as
//   mine[p][q] = partner_swap(partner[norm(p^4, q^4)]).
//
// R6 (matrix Horner): intermediates are polynomials in A -> symmetric,
// commute with A. Build R = w6 A^6 + ... + w0 I via 5 upper-triangle
// symmetric products, M = R A + (1+w7) I (6th), then ONE matvec out = M x.
// Per step: 20 entries computed locally, 16 received from partner lane.
//
// R10 change: partner exchange via DPP quad_perm, not __shfl_xor.
// __shfl_xor(x,1) lowers to ds_bpermute (DS pipe, lgkmcnt latency) + index
// math; this kernel has 132 of them per lane and each MAT_STEP depends on
// the previous step's received entries, so at ~2 waves/SIMD the DS latency
// is exposed -> VALUBusy 49%. quad_perm([1,0,3,2]) (ctrl 0xB1) does the
// lane^1 swap as a single VALU v_mov_b32_dpp: no DS pipe, no waits.
// Also reverts R9's __launch_bounds__(256,4): that forced VGPR 116->64 and
// spilled to scratch (FETCH 276MB, WRITE 489MB, 190us). (256,2) compiles
// clean at 116 VGPR.
//
// Code-shape lesson (R2-R5): plain [8][8] arrays, upper-triangle writes only
// (dead elements SROA away), no packing.

#define SE(p, q) S[(p) < (q) ? (p) : (q)][(p) < (q) ? (q) : (p)]
#define AE(p, q) A[(p) < (q) ? (p) : (q)][(p) < (q) ? (q) : (p)]
#define UT(M, p, q) M[(p) < (q) ? (p) : (q)][(p) < (q) ? (q) : (p)]
// Lane-split membership for symmetric-product entries (upper triangle):
// computed set T = {q<4 (UL)} u {p+4<=q (chosen crossing + fixed points)}.
#define IN_T(p, q) ((q) < 4 || (p) + 4 <= (q))

// lane^1 partner swap as DPP quad_perm [1,0,3,2] (ctrl 0xB1): single VALU op.
// All 64 lanes are always active here, so bound_ctrl/masks are trivial.
__device__ __forceinline__ float pswap(float x)
{
    return __builtin_bit_cast(float,
        __builtin_amdgcn_update_dpp(0, __builtin_bit_cast(int, x),
                                    0xB1, 0xF, 0xF, true));
}

// One matrix-Horner step: Pn = Po * A + wk * I  (all symmetric, upper only).
// Compute 20 entries locally, receive 16 from the partner lane via DPP.
#define MAT_STEP(Pn, Po, wk)                                              \
    {                                                                     \
        _Pragma("unroll")                                                 \
        for (int p = 0; p < 8; ++p) {                                     \
            _Pragma("unroll")                                             \
            for (int q = p; q < 8; ++q) {                                 \
                if (IN_T(p, q)) {                                         \
                    float s = (p == q) ? (wk) : 0.0f;                     \
                    _Pragma("unroll")                                     \
                    for (int r = 0; r < 8; ++r)                           \
                        s += UT(Po, p, r) * AE(r, q);                     \
                    Pn[p][q] = s;                                         \
                }                                                         \
            }                                                             \
        }                                                                 \
        _Pragma("unroll")                                                 \
        for (int p = 0; p < 8; ++p) {                                     \
            _Pragma("unroll")                                             \
            for (int q = p; q < 8; ++q) {                                 \
                if (!IN_T(p, q)) {                                        \
                    const int pa = (p) ^ 4, pb = (q) ^ 4;                 \
                    const int lo = pa < pb ? pa : pb;                     \
                    const int hi = pa < pb ? pb : pa;                     \
                    Pn[p][q] = pswap(Pn[lo][hi]);                         \
                }                                                         \
            }                                                             \
        }                                                                 \
    }

__global__ __launch_bounds__(256, 2)
void ns_poly_kernel(const float* __restrict__ in,
                    const float* __restrict__ wp,
                    float* __restrict__ out)
{
    const int tid = threadIdx.x;
    const int m   = blockIdx.x * 128 + (tid >> 1);   // matrix index
    const int h   = tid & 1;                          // column-half owner

    const float w0 = wp[0], w1 = wp[1], w2 = wp[2], w3 = wp[3];
    const float w4 = wp[4], w5 = wp[5], w6 = wp[6], w7 = wp[7];

    // ---- direct column-fragment loads (transpose by addressing) ----
    const float* bp      = in + (size_t)m * 64 + h * 4;
    const float* baseOwn = bp + h * 32;
    const float* basePar = bp + (1 - h) * 32;

    float xc[4][8];                                   // xc[jj][p]: col 4h+jj, permuted row p
#pragma unroll
    for (int p = 0; p < 4; ++p) {
        const float4 v = *reinterpret_cast<const float4*>(baseOwn + p * 8);
        xc[0][p] = v.x; xc[1][p] = v.y; xc[2][p] = v.z; xc[3][p] = v.w;
    }
#pragma unroll
    for (int p = 0; p < 4; ++p) {
        const float4 v = *reinterpret_cast<const float4*>(basePar + p * 8);
        xc[0][4 + p] = v.x; xc[1][4 + p] = v.y; xc[2][4 + p] = v.z; xc[3][4 + p] = v.w;
    }

    // ---- partial Gram S[p][q] = sum over my 4 columns (upper triangle) ----
    float S[8][8];
#pragma unroll
    for (int p = 0; p < 8; ++p)
#pragma unroll
        for (int q = p; q < 8; ++q) {
            float s = xc[0][p] * xc[0][q];
            s += xc[1][p] * xc[1][q];
            s += xc[2][p] * xc[2][q];
            s += xc[3][p] * xc[3][q];
            S[p][q] = s;
        }

    // ---- A = I - S - partner(S) (one DPP swap per entry) ----
    float A[8][8];
#pragma unroll
    for (int p = 0; p < 8; ++p)
#pragma unroll
        for (int q = p; q < 8; ++q) {
            const float other = pswap(SE((p) ^ 4, (q) ^ 4));
            A[p][q] = (p == q ? 1.0f : 0.0f) - S[p][q] - other;
        }

    // ---- matrix Horner on the upper triangle ----
    // P = w6 A + w5 I (elementwise init, full upper triangle)
    float P[8][8], Q[8][8];
#pragma unroll
    for (int p = 0; p < 8; ++p)
#pragma unroll
        for (int q = p; q < 8; ++q)
            P[p][q] = (p == q) ? fmaf(w6, A[p][q], w5) : w6 * A[p][q];

    MAT_STEP(Q, P, w4);           // w6 A^2 + w5 A + w4 I
    MAT_STEP(P, Q, w3);
    MAT_STEP(Q, P, w2);
    MAT_STEP(P, Q, w1);
    MAT_STEP(Q, P, w0);           // R = w6 A^6 + ... + w0 I
    MAT_STEP(P, Q, 1.0f + w7);    // M = R A + (1+w7) I

    // ---- single matvec: out columns = M * x columns (shuffle-free) ----
    float t[4][8];
#pragma unroll
    for (int jj = 0; jj < 4; ++jj)
#pragma unroll
        for (int p = 0; p < 8; ++p) {
            float s = UT(P, p, 0) * xc[jj][0];
#pragma unroll
            for (int q = 1; q < 8; ++q)
                s += UT(P, p, q) * xc[jj][q];
            t[jj][p] = s;
        }

    // ---- direct column-fragment stores (transpose by addressing) ----
    float* obp     = out + (size_t)m * 64 + h * 4;
    float* oandOwn = obp + h * 32;
    float* oandPar = obp + (1 - h) * 32;
#pragma unroll
    for (int p = 0; p < 4; ++p)
        *reinterpret_cast<float4*>(oandOwn + p * 8) =
            make_float4(t[0][p], t[1][p], t[2][p], t[3][p]);
#pragma unroll
    for (int p = 0; p < 4; ++p)
        *reinterpret_cast<float4*>(oandPar + p * 8) =
            make_float4(t[0][4 + p], t[1][4 + p], t[2][4 + p], t[3][4 + p]);
}

extern "C" void kernel_launch(void* const* d_in, const int* in_sizes, int n_in,
                              void* d_out, int out_size, void* d_ws, size_t ws_size,
                              hipStream_t stream)
{
    const float* in = (const float*)d_in[0];
    const float* w  = (const float*)d_in[1];
    float* outp     = (float*)d_out;

    const int nmat   = in_sizes[0] / 64;   // 262144 matrices
    const int blocks = nmat / 128;         // 128 matrices per 256-thread block
    ns_poly_kernel<<<blocks, 256, 0, stream>>>(in, w, outp);
}